// Round 11
// baseline (224.259 us; speedup 1.0000x reference)
//
#include <hip/hip_runtime.h>
#include <hip/hip_bf16.h>
#include <math.h>

// Problem constants: B=2, N=2048, C=1024, H=16, D=64; M = B*N = 4096.

typedef __attribute__((ext_vector_type(8))) short bf16x8;  // 8 bf16 (4 VGPR)
typedef __attribute__((ext_vector_type(4))) short bf16x4;  // 4 bf16 (2 VGPR)
typedef __attribute__((ext_vector_type(4))) float f32x4;
typedef __attribute__((ext_vector_type(2))) unsigned int u32x2;

__device__ __forceinline__ short f2bf(float f) {
    union { float f; unsigned u; } x; x.f = f;
    unsigned r = x.u + 0x7fffu + ((x.u >> 16) & 1u);   // round-to-nearest-even
    return (short)(r >> 16);
}

__device__ __forceinline__ unsigned cvt_pk_bf16(float lo, float hi) {
    asm("" ::: );  // keep simple
    unsigned r;
    asm("v_cvt_pk_bf16_f32 %0, %1, %2" : "=v"(r) : "v"(lo), "v"(hi));
    return r;  // low16 = bf16(lo), high16 = bf16(hi)  (RNE)
}

__device__ __forceinline__ float fast_exp2(float x) {
#if __has_builtin(__builtin_amdgcn_exp2f)
    return __builtin_amdgcn_exp2f(x);
#else
    return exp2f(x);
#endif
}

union BF8U { unsigned u[4]; bf16x8 v; };
union BF4U { unsigned u[2]; bf16x4 v; };

// ---------------------------------------------------------------------------
// Weight prep: W (K x N, f32) -> Wt (N x K, bf16), 4 matrices via blockIdx.z
// ---------------------------------------------------------------------------
__global__ __launch_bounds__(256) void prep_w(const float* __restrict__ Wq,
                                              const float* __restrict__ Wk,
                                              const float* __restrict__ Wv,
                                              const float* __restrict__ Wo,
                                              short* __restrict__ wt) {
    __shared__ float tile[32][33];
    const float* W = blockIdx.z == 0 ? Wq : blockIdx.z == 1 ? Wk
                   : blockIdx.z == 2 ? Wv : Wo;
    short* dst = wt + (size_t)blockIdx.z * 1048576;
    const int bx = blockIdx.x * 32, by = blockIdx.y * 32;
    const int tx = threadIdx.x & 31, ty = threadIdx.x >> 5;  // 32 x 8
#pragma unroll
    for (int i = 0; i < 32; i += 8)
        tile[ty + i][tx] = W[(size_t)(by + ty + i) * 1024 + bx + tx];
    __syncthreads();
#pragma unroll
    for (int i = 0; i < 32; i += 8)
        dst[(size_t)(bx + ty + i) * 1024 + by + tx] = f2bf(tile[tx][ty + i]);
}

// ---------------------------------------------------------------------------
// Fused QKV GEMM: out_z = A_z(4096x1024,f32) @ Wt_z^T + bias_z.  BM=128 BN=64,
// 2-phase load-ahead pipeline. cvt_pk (packed bf16 convert) in staging.
// blockIdx.z: 0=Q (scale, scatter [b,h,n,d]), 1=K (scatter), 2=V (scatter^T).
// ---------------------------------------------------------------------------
__global__ __launch_bounds__(256) void gemm_qkv(const float* __restrict__ qA,
                                                const float* __restrict__ kA,
                                                const float* __restrict__ vA,
                                                const short* __restrict__ wt,
                                                const float* __restrict__ bq,
                                                const float* __restrict__ bk,
                                                const float* __restrict__ bv,
                                                short* __restrict__ qh,
                                                short* __restrict__ khp,
                                                short* __restrict__ vtp,
                                                float qscale) {
    __shared__ short As[128 * 32];  // 8 KiB
    __shared__ short Bs[64 * 32];   // 4 KiB
    const int tid = threadIdx.x;
    const int l = tid & 63, w = tid >> 6;
    const int wr = w >> 1, wc = w & 1;
    const int row16 = l & 15, lg = l >> 4;
    const int m0 = blockIdx.x * 128;
    const int n0 = blockIdx.y * 64;
    const int z = blockIdx.z;

    const float* A = z == 0 ? qA : z == 1 ? kA : vA;
    const short* Wt = wt + (size_t)z * 1048576;
    const float* bias = z == 0 ? bq : z == 1 ? bk : bv;
    const float scale = z == 0 ? qscale : 1.0f;
    short* outp = z == 0 ? qh : z == 1 ? khp : vtp;

    const int ar = tid >> 1, ac = (tid & 1) * 16;   // A: 128 rows x 32 cols
    const int br = tid >> 2, bc = (tid & 3) * 8;    // B: 64 rows x 32 cols

    f32x4 acc[4][2] = {};

    f32x4 x0, x1, x2, x3; bf16x8 bfrag;
    {
        const float* src = A + (size_t)(m0 + ar) * 1024 + ac;
        x0 = ((const f32x4*)src)[0]; x1 = ((const f32x4*)src)[1];
        x2 = ((const f32x4*)src)[2]; x3 = ((const f32x4*)src)[3];
        bfrag = *(const bf16x8*)(Wt + (size_t)(n0 + br) * 1024 + bc);
    }

    for (int t = 0; t < 32; ++t) {
        __syncthreads();  // all frag reads of tile t-1 complete
        BF8U u0, u1;
        u0.u[0] = cvt_pk_bf16(x0[0], x0[1]); u0.u[1] = cvt_pk_bf16(x0[2], x0[3]);
        u0.u[2] = cvt_pk_bf16(x1[0], x1[1]); u0.u[3] = cvt_pk_bf16(x1[2], x1[3]);
        u1.u[0] = cvt_pk_bf16(x2[0], x2[1]); u1.u[1] = cvt_pk_bf16(x2[2], x2[3]);
        u1.u[2] = cvt_pk_bf16(x3[0], x3[1]); u1.u[3] = cvt_pk_bf16(x3[2], x3[3]);
        *(bf16x8*)&As[ar * 32 + ac]     = u0.v;
        *(bf16x8*)&As[ar * 32 + ac + 8] = u1.v;
        *(bf16x8*)&Bs[br * 32 + bc]     = bfrag;
        __syncthreads();
        if (t < 31) {   // issue next tile's globals; latency hides under MFMA
            const int k0 = (t + 1) * 32;
            const float* src = A + (size_t)(m0 + ar) * 1024 + k0 + ac;
            x0 = ((const f32x4*)src)[0]; x1 = ((const f32x4*)src)[1];
            x2 = ((const f32x4*)src)[2]; x3 = ((const f32x4*)src)[3];
            bfrag = *(const bf16x8*)(Wt + (size_t)(n0 + br) * 1024 + k0 + bc);
        }
        bf16x8 af[4], bf2[2];
#pragma unroll
        for (int m = 0; m < 4; ++m)
            af[m] = *(const bf16x8*)&As[(wr * 64 + m * 16 + row16) * 32 + lg * 8];
#pragma unroll
        for (int n = 0; n < 2; ++n)
            bf2[n] = *(const bf16x8*)&Bs[(wc * 32 + n * 16 + row16) * 32 + lg * 8];
#pragma unroll
        for (int m = 0; m < 4; ++m)
#pragma unroll
            for (int n = 0; n < 2; ++n)
                acc[m][n] = __builtin_amdgcn_mfma_f32_16x16x32_bf16(af[m], bf2[n], acc[m][n], 0, 0, 0);
    }

    // Epilogue. C/D layout: col = lane&15, row = (lane>>4)*4 + reg.
#pragma unroll
    for (int n = 0; n < 2; ++n) {
        const int col = n0 + wc * 32 + n * 16 + row16;
        const float bvl = bias[col];
        const int h = col >> 6, d = col & 63;
#pragma unroll
        for (int m = 0; m < 4; ++m) {
#pragma unroll
            for (int r = 0; r < 4; ++r) {
                const int row = m0 + wr * 64 + m * 16 + lg * 4 + r;
                const float val = (acc[m][n][r] + bvl) * scale;
                const int b = row >> 11, nt = row & 2047;
                if (z != 2)
                    outp[(((size_t)(b * 16 + h)) * 2048 + nt) * 64 + d] = f2bf(val);
                else
                    outp[(((size_t)(b * 16 + h)) * 64 + d) * 2048 + nt] = f2bf(val);
            }
        }
    }
}

// ---------------------------------------------------------------------------
// Final GEMM: d_out = aout(4096x1024,bf16) @ Wo^T + bo, f32 out.
// ---------------------------------------------------------------------------
__global__ __launch_bounds__(256) void gemm_out(const short* __restrict__ Ab,
                                                const short* __restrict__ Wt,
                                                const float* __restrict__ bias,
                                                float* __restrict__ outp) {
    __shared__ short As[128 * 32];
    __shared__ short Bs[64 * 32];
    const int tid = threadIdx.x;
    const int l = tid & 63, w = tid >> 6;
    const int wr = w >> 1, wc = w & 1;
    const int row16 = l & 15, lg = l >> 4;
    const int m0 = blockIdx.x * 128;
    const int n0 = blockIdx.y * 64;

    const int ar = tid >> 1, ac = (tid & 1) * 16;
    const int br = tid >> 2, bc = (tid & 3) * 8;

    f32x4 acc[4][2] = {};

    bf16x8 sa0, sa1, bfrag;
    sa0 = *(const bf16x8*)(Ab + (size_t)(m0 + ar) * 1024 + ac);
    sa1 = *(const bf16x8*)(Ab + (size_t)(m0 + ar) * 1024 + ac + 8);
    bfrag = *(const bf16x8*)(Wt + (size_t)(n0 + br) * 1024 + bc);

    for (int t = 0; t < 32; ++t) {
        __syncthreads();
        *(bf16x8*)&As[ar * 32 + ac]     = sa0;
        *(bf16x8*)&As[ar * 32 + ac + 8] = sa1;
        *(bf16x8*)&Bs[br * 32 + bc]     = bfrag;
        __syncthreads();
        if (t < 31) {
            const int k0 = (t + 1) * 32;
            sa0 = *(const bf16x8*)(Ab + (size_t)(m0 + ar) * 1024 + k0 + ac);
            sa1 = *(const bf16x8*)(Ab + (size_t)(m0 + ar) * 1024 + k0 + ac + 8);
            bfrag = *(const bf16x8*)(Wt + (size_t)(n0 + br) * 1024 + k0 + bc);
        }
        bf16x8 af[4], bf2[2];
#pragma unroll
        for (int m = 0; m < 4; ++m)
            af[m] = *(const bf16x8*)&As[(wr * 64 + m * 16 + row16) * 32 + lg * 8];
#pragma unroll
        for (int n = 0; n < 2; ++n)
            bf2[n] = *(const bf16x8*)&Bs[(wc * 32 + n * 16 + row16) * 32 + lg * 8];
#pragma unroll
        for (int m = 0; m < 4; ++m)
#pragma unroll
            for (int n = 0; n < 2; ++n)
                acc[m][n] = __builtin_amdgcn_mfma_f32_16x16x32_bf16(af[m], bf2[n], acc[m][n], 0, 0, 0);
    }

#pragma unroll
    for (int n = 0; n < 2; ++n) {
        const int col = n0 + wc * 32 + n * 16 + row16;
        const float bvl = bias[col];
#pragma unroll
        for (int m = 0; m < 4; ++m) {
#pragma unroll
            for (int r = 0; r < 4; ++r) {
                const int row = m0 + wr * 64 + m * 16 + lg * 4 + r;
                outp[(size_t)row * 1024 + col] = acc[m][n][r] + bvl;
            }
        }
    }
}

// ---------------------------------------------------------------------------
// Flash attention v11 = r8 datapath (verified) + split-KV x2 for occupancy.
// SPLIT=1: blockIdx.z selects half of the KV range (16 tiles); unnormalized
// O and l written to f32 partials (no-max softmax => combine is exactly
// linear: O = (O0+O1)/(l0+l1)). 4096 waves = 4/SIMD (VGPR cap) vs r8's 2.
// SPLIT=0: identical to r8 single-pass (fallback when ws too small).
// Fenced per-wave P-LDS roundtrip; l via MFMA(P, ones); XCD swizzle (r8:
// FETCH 70->12 MB); K prefetch distance 2, V distance 1.
// ---------------------------------------------------------------------------
__device__ __forceinline__ void attn_step(int t, int b0, int mask,
                                          const short* __restrict__ kbase,
                                          const short* __restrict__ vbase,
                                          bf16x8 (&kc)[4][2],   // K[t] in, K[t+2] out
                                          bf16x8 (&vf)[4][2],   // V[t-1] in, V[t] out
                                          bf16x8 (&qf)[2][2], bf16x8 (&pf)[2][2],
                                          f32x4 (&oac)[2][4], f32x4 (&lacc)[2],
                                          const bf16x8& ones,
                                          short* prow0, short* prow1,
                                          int row16, int lg) {
    const int kvn = t * 64;
    const int kvp = (b0 + ((t + 2 - b0) & mask)) * 64;   // wrap: harmless
    short* prow[2] = {prow0, prow1};

    // QK^T (swapped): s[qt][kt] = S^T[k=kvn+kt*16+lg*4+r][q=qt*16+row16].
    f32x4 s[2][4] = {};
#pragma unroll
    for (int kt = 0; kt < 4; ++kt)
#pragma unroll
        for (int kk = 0; kk < 2; ++kk) {
            s[0][kt] = __builtin_amdgcn_mfma_f32_16x16x32_bf16(kc[kt][kk], qf[0][kk], s[0][kt], 0, 0, 0);
            s[1][kt] = __builtin_amdgcn_mfma_f32_16x16x32_bf16(kc[kt][kk], qf[1][kk], s[1][kt], 0, 0, 0);
        }
    // Prefetch K[t+2] into the same buffer (free after the QK above).
#pragma unroll
    for (int kt = 0; kt < 4; ++kt)
#pragma unroll
        for (int kk = 0; kk < 2; ++kk)
            kc[kt][kk] = *(const bf16x8*)&kbase[(size_t)(kvp + kt * 16 + row16) * 64 + kk * 32 + lg * 8];

    // exp (native) + P-store.
#pragma unroll
    for (int qt = 0; qt < 2; ++qt)
#pragma unroll
        for (int kt = 0; kt < 4; ++kt) {
            u32x2 pk;
            pk.x = cvt_pk_bf16(fast_exp2(s[qt][kt][0]), fast_exp2(s[qt][kt][1]));
            pk.y = cvt_pk_bf16(fast_exp2(s[qt][kt][2]), fast_exp2(s[qt][kt][3]));
            *(u32x2*)&prow[qt][kt * 16 + lg * 4] = pk;
        }

    // PV[t-1] (pf, vf carried from previous step; overlaps the exp chain).
#pragma unroll
    for (int dt = 0; dt < 4; ++dt)
#pragma unroll
        for (int kk = 0; kk < 2; ++kk) {
            oac[0][dt] = __builtin_amdgcn_mfma_f32_16x16x32_bf16(pf[0][kk], vf[dt][kk], oac[0][dt], 0, 0, 0);
            oac[1][dt] = __builtin_amdgcn_mfma_f32_16x16x32_bf16(pf[1][kk], vf[dt][kk], oac[1][dt], 0, 0, 0);
        }
#pragma unroll
    for (int qt = 0; qt < 2; ++qt)
#pragma unroll
        for (int kk = 0; kk < 2; ++kk)
            lacc[qt] = __builtin_amdgcn_mfma_f32_16x16x32_bf16(pf[qt][kk], ones, lacc[qt], 0, 0, 0);

    // Load V[t] (vf free after PV[t-1]; consumed next step).
#pragma unroll
    for (int dt = 0; dt < 4; ++dt)
#pragma unroll
        for (int kk = 0; kk < 2; ++kk)
            vf[dt][kk] = *(const bf16x8*)&vbase[(size_t)(dt * 16 + row16) * 2048 + kvn + kk * 32 + lg * 8];

    asm volatile("s_waitcnt lgkmcnt(0)" ::: "memory");
#pragma unroll
    for (int qt = 0; qt < 2; ++qt)
#pragma unroll
        for (int kk = 0; kk < 2; ++kk)
            pf[qt][kk] = *(const bf16x8*)&prow[qt][kk * 32 + lg * 8];
    asm volatile("" ::: "memory");  // next stores must not hoist above reads
}

template <int SPLIT>
__global__ __launch_bounds__(256) void attn_kernel(const short* __restrict__ qh,
                                                   const short* __restrict__ kh,
                                                   const short* __restrict__ vt,
                                                   short* __restrict__ aout,
                                                   float* __restrict__ part,
                                                   float* __restrict__ lpart) {
    __shared__ short Pls[8][16 * 72];   // [wave*2+qt][q][k], padded rows

    const int tid = threadIdx.x;
    const int l = tid & 63, w = tid >> 6;
    const int row16 = l & 15, lg = l >> 4;

    // XCD swizzle: fid%8 = XCD. Each XCD owns 4 whole heads (2 MB K/V in L2).
    // (grid z adds multiples of 512 to the linear id; 512%8==0 keeps it valid.)
    const int fid = blockIdx.y * 16 + blockIdx.x;       // grid (16, 32[, 2])
    const int xcd = fid & 7, slot = fid >> 3;
    const int bh = xcd * 4 + (slot >> 4);
    const int q0 = (slot & 15) * 128 + w * 32;
    const int z = SPLIT ? blockIdx.z : 0;
    const int b0 = SPLIT ? z * 16 : 0;
    const int NT = SPLIT ? 16 : 32;
    const int mask = NT - 1;

    const short* kbase = kh + (size_t)bh * 2048 * 64;
    const short* vbase = vt + (size_t)bh * 64 * 2048;

    bf16x8 qf[2][2];
#pragma unroll
    for (int qt = 0; qt < 2; ++qt)
#pragma unroll
        for (int kk = 0; kk < 2; ++kk)
            qf[qt][kk] = *(const bf16x8*)&qh[((size_t)bh * 2048 + q0 + qt * 16 + row16) * 64 + kk * 32 + lg * 8];

    bf16x8 ones;
#pragma unroll
    for (int j = 0; j < 8; ++j) ones[j] = (short)0x3F80;  // bf16 1.0

    f32x4 oac[2][4] = {};
    f32x4 lacc[2] = {};

    short* prow0 = &Pls[w * 2 + 0][row16 * 72];
    short* prow1 = &Pls[w * 2 + 1][row16 * 72];
    short* prow[2] = {prow0, prow1};

    // Preload K[b0] (kfA), K[b0+1] (kfB), V[b0].
    bf16x8 kfA[4][2], kfB[4][2], vf[4][2], pf[2][2];
#pragma unroll
    for (int kt = 0; kt < 4; ++kt)
#pragma unroll
        for (int kk = 0; kk < 2; ++kk) {
            kfA[kt][kk] = *(const bf16x8*)&kbase[(size_t)((b0 + 0) * 64 + kt * 16 + row16) * 64 + kk * 32 + lg * 8];
            kfB[kt][kk] = *(const bf16x8*)&kbase[(size_t)((b0 + 1) * 64 + kt * 16 + row16) * 64 + kk * 32 + lg * 8];
            vf[kt][kk]  = *(const bf16x8*)&vbase[(size_t)(kt * 16 + row16) * 2048 + b0 * 64 + kk * 32 + lg * 8];
        }

    // ---- iter b0 (no PV): QK, prefetch kfA<-K[b0+2], exp/store P, read pf.
    {
        f32x4 s[2][4] = {};
#pragma unroll
        for (int kt = 0; kt < 4; ++kt)
#pragma unroll
            for (int kk = 0; kk < 2; ++kk) {
                s[0][kt] = __builtin_amdgcn_mfma_f32_16x16x32_bf16(kfA[kt][kk], qf[0][kk], s[0][kt], 0, 0, 0);
                s[1][kt] = __builtin_amdgcn_mfma_f32_16x16x32_bf16(kfA[kt][kk], qf[1][kk], s[1][kt], 0, 0, 0);
            }
#pragma unroll
        for (int kt = 0; kt < 4; ++kt)
#pragma unroll
            for (int kk = 0; kk < 2; ++kk)
                kfA[kt][kk] = *(const bf16x8*)&kbase[(size_t)((b0 + 2) * 64 + kt * 16 + row16) * 64 + kk * 32 + lg * 8];
#pragma unroll
        for (int qt = 0; qt < 2; ++qt)
#pragma unroll
            for (int kt = 0; kt < 4; ++kt) {
                u32x2 pk;
                pk.x = cvt_pk_bf16(fast_exp2(s[qt][kt][0]), fast_exp2(s[qt][kt][1]));
                pk.y = cvt_pk_bf16(fast_exp2(s[qt][kt][2]), fast_exp2(s[qt][kt][3]));
                *(u32x2*)&prow[qt][kt * 16 + lg * 4] = pk;
            }
        asm volatile("s_waitcnt lgkmcnt(0)" ::: "memory");
#pragma unroll
        for (int qt = 0; qt < 2; ++qt)
#pragma unroll
            for (int kk = 0; kk < 2; ++kk)
                pf[qt][kk] = *(const bf16x8*)&prow[qt][kk * 32 + lg * 8];
        asm volatile("" ::: "memory");
    }

    // ---- steps b0+1 .. b0+NT-2 in pairs, then b0+NT-1 (kfB/kfA alternation).
    for (int tt = b0 + 1; tt < b0 + NT - 1; tt += 2) {
        attn_step(tt,     b0, mask, kbase, vbase, kfB, vf, qf, pf, oac, lacc, ones, prow0, prow1, row16, lg);
        attn_step(tt + 1, b0, mask, kbase, vbase, kfA, vf, qf, pf, oac, lacc, ones, prow0, prow1, row16, lg);
    }
    attn_step(b0 + NT - 1, b0, mask, kbase, vbase, kfB, vf, qf, pf, oac, lacc, ones, prow0, prow1, row16, lg);

    // ---- epilogue: PV[last] + l.
#pragma unroll
    for (int dt = 0; dt < 4; ++dt)
#pragma unroll
        for (int kk = 0; kk < 2; ++kk) {
            oac[0][dt] = __builtin_amdgcn_mfma_f32_16x16x32_bf16(pf[0][kk], vf[dt][kk], oac[0][dt], 0, 0, 0);
            oac[1][dt] = __builtin_amdgcn_mfma_f32_16x16x32_bf16(pf[1][kk], vf[dt][kk], oac[1][dt], 0, 0, 0);
        }
#pragma unroll
    for (int qt = 0; qt < 2; ++qt)
#pragma unroll
        for (int kk = 0; kk < 2; ++kk)
            lacc[qt] = __builtin_amdgcn_mfma_f32_16x16x32_bf16(pf[qt][kk], ones, lacc[qt], 0, 0, 0);

    if constexpr (SPLIT) {
        // Unnormalized O + l to f32 partials (combine is linear: no-max softmax).
        float* pb = part + (size_t)z * 4194304 + (size_t)bh * 2048 * 64;
        float* lb = lpart + (size_t)z * 65536 + (size_t)bh * 2048;
#pragma unroll
        for (int qt = 0; qt < 2; ++qt)
#pragma unroll
            for (int r = 0; r < 4; ++r) {
                const int qrow = q0 + qt * 16 + lg * 4 + r;
#pragma unroll
                for (int dt = 0; dt < 4; ++dt)
                    pb[(size_t)qrow * 64 + dt * 16 + row16] = oac[qt][dt][r];
            }
        if (row16 == 0) {
#pragma unroll
            for (int qt = 0; qt < 2; ++qt)
#pragma unroll
                for (int r = 0; r < 4; ++r)
                    lb[q0 + qt * 16 + lg * 4 + r] = lacc[qt][r];
        }
    } else {
        const int b = bh >> 4, h = bh & 15;
#pragma unroll
        for (int qt = 0; qt < 2; ++qt) {
#pragma unroll
            for (int r = 0; r < 4; ++r) {
                const float iv = 1.f / lacc[qt][r];
                const int qrow = q0 + qt * 16 + lg * 4 + r;
#pragma unroll
                for (int dt = 0; dt < 4; ++dt) {
                    const int c = h * 64 + dt * 16 + row16;
                    aout[((size_t)b * 2048 + qrow) * 1024 + c] = f2bf(oac[qt][dt][r] * iv);
                }
            }
        }
    }
}

// ---------------------------------------------------------------------------
// Combine: O = (O0 + O1) / (l0 + l1), f32 partials -> bf16 aout[b,n,c].
// ---------------------------------------------------------------------------
__global__ __launch_bounds__(256) void attn_combine(const float* __restrict__ part,
                                                    const float* __restrict__ lpart,
                                                    short* __restrict__ aout) {
    const int g = blockIdx.x * 256 + threadIdx.x;   // 1,048,576 threads
    const int c4 = g & 15;
    const int q  = (g >> 4) & 2047;
    const int bh = g >> 15;
    const size_t po = ((size_t)bh * 2048 + q) * 64 + c4 * 4;
    f32x4 p0 = *(const f32x4*)&part[po];
    f32x4 p1 = *(const f32x4*)&part[4194304 + po];
    const float lsum = lpart[bh * 2048 + q] + lpart[65536 + bh * 2048 + q];
    const float iv = 1.f / lsum;
    BF4U o;
    o.u[0] = cvt_pk_bf16((p0[0] + p1[0]) * iv, (p0[1] + p1[1]) * iv);
    o.u[1] = cvt_pk_bf16((p0[2] + p1[2]) * iv, (p0[3] + p1[3]) * iv);
    const int b = bh >> 4, h = bh & 15;
    *(bf16x4*)&aout[((size_t)b * 2048 + q) * 1024 + h * 64 + c4 * 4] = o.v;
}

// ---------------------------------------------------------------------------
extern "C" void kernel_launch(void* const* d_in, const int* in_sizes, int n_in,
                              void* d_out, int out_size, void* d_ws, size_t ws_size,
                              hipStream_t stream) {
    const float* q  = (const float*)d_in[0];
    const float* k  = (const float*)d_in[1];
    const float* v  = (const float*)d_in[2];
    const float* Wq = (const float*)d_in[3];
    const float* bq = (const float*)d_in[4];
    const float* Wk = (const float*)d_in[5];
    const float* bk = (const float*)d_in[6];
    const float* Wv = (const float*)d_in[7];
    const float* bv = (const float*)d_in[8];
    const float* Wo = (const float*)d_in[9];
    const float* bo = (const float*)d_in[10];

    char* ws = (char*)d_ws;
    short* wt   = (short*)ws;                     // 4 x 2 MiB bf16 W^T
    short* qh   = (short*)(ws + (8u  << 20));     // 8 MiB [b,h,n,d]
    short* khp  = (short*)(ws + (16u << 20));     // 8 MiB [b,h,n,d]
    short* vt   = (short*)(ws + (24u << 20));     // 8 MiB [b,h,d,n]
    short* aout = (short*)(ws + (32u << 20));     // 8 MiB [b,n,c]
    float* part = (float*)(ws + (40u << 20));     // 2 x 16 MiB f32 partial O
    float* lprt = (float*)(ws + (72u << 20));     // 2 x 256 KiB f32 partial l

    const float qscale = 0.125f * 1.44269504088896340736f;  // 1/sqrt(D) * log2(e)
    const bool split = ws_size >= (76ull << 20);

    prep_w<<<dim3(32, 32, 4), 256, 0, stream>>>(Wq, Wk, Wv, Wo, wt);
    gemm_qkv<<<dim3(32, 16, 3), 256, 0, stream>>>(q, k, v, wt, bq, bk, bv,
                                                  qh, khp, vt, qscale);
    if (split) {
        attn_kernel<1><<<dim3(16, 32, 2), 256, 0, stream>>>(qh, khp, vt, aout, part, lprt);
        attn_combine<<<4096, 256, 0, stream>>>(part, lprt, aout);
    } else {
        attn_kernel<0><<<dim3(16, 32), 256, 0, stream>>>(qh, khp, vt, aout, nullptr, nullptr);
    }
    gemm_out<<<dim3(32, 16), 256, 0, stream>>>(aout, wt + 3145728, bo, (float*)d_out);
}